// Round 3
// baseline (45.326 us; speedup 1.0000x reference)
//
#include <hip/hip_runtime.h>

#define NBATCH 1024
#define NELEC  64
#define NBAS   256
#define NORB   128
#define NROWS  (NBATCH * NELEC)
#define RPW    4                       // rows per wave
#define WPB    4                       // waves per block (256 threads)
#define ROWS_PER_BLOCK (RPW * WPB)

// d_ws layout (dwords): [0,4096) = per-basis params, 16 floats each:
//   {nex, cc, cx, cy, cz, a0,a1,a2,a3, b0,b1,b2,b3, c9, 0, 0}
// [4096, 4225) = start[129] (int)   -> total 16.9 KB
#define WS_PARAM_DW 0
#define WS_START_DW 4096

__global__ void setup_kernel(
    const float* __restrict__ atom_coords,
    const float* __restrict__ bas_exp,
    const float* __restrict__ bas_coeffs,
    const float* __restrict__ norm_cst,
    const int*   __restrict__ bas_l,
    const int*   __restrict__ bas_m,
    const int*   __restrict__ bas_atom_index,
    const int*   __restrict__ index_ctr,
    float* __restrict__ ws)
{
    const int j = threadIdx.x;
    if (j < NBAS) {
        float ex = bas_exp[j];
        float cc = norm_cst[j] * bas_coeffs[j];
        int l = bas_l[j], m = bas_m[j];
        int ai = bas_atom_index[j];
        float cx = atom_coords[ai*3+0], cy = atom_coords[ai*3+1], cz = atom_coords[ai*3+2];
        const float C0 = 0.2820948f, C1 = 0.4886025f, C2XY = 1.0925484f,
                    C2Z2 = 0.31539156f, C2D = 0.5462742f;
        float a0=0.f,a1=0.f,a2=0.f,a3=0.f, b0=0.f,b1=0.f,b2=0.f,b3=0.f, c9=0.f;
        if (l == 0)            { cc *= C0; a3 = 1.f; b3 = 1.f; }
        else if (l == 1) {
            cc *= C1; b3 = 1.f;
            if      (m == -1) a1 = 1.f;
            else if (m ==  0) a2 = 1.f;
            else              a0 = 1.f;
        } else {
            if      (m == -2) { cc *= C2XY; a0 = 1.f; b1 = 1.f; }            // xy
            else if (m == -1) { cc *= C2XY; a1 = 1.f; b2 = 1.f; }            // yz
            else if (m ==  0) { cc *= 3.0f*C2Z2; a2 = 1.f; b2 = 1.f; c9 = -1.0f/3.0f; } // zz - r2/3
            else if (m ==  1) { cc *= C2XY; a2 = 1.f; b0 = 1.f; }            // zx
            else              { cc *= C2D;  a0 = 1.f; a1 = 1.f; b0 = 1.f; b1 = -1.f; }  // (x+y)(x-y)
        }
        float* p = ws + WS_PARAM_DW + j*16;
        p[0] = -ex * 1.4426950408889634f;  // fold log2(e) for v_exp_f32
        p[1] = cc; p[2] = cx; p[3] = cy; p[4] = cz;
        p[5] = a0; p[6] = a1; p[7] = a2; p[8] = a3;
        p[9] = b0; p[10] = b1; p[11] = b2; p[12] = b3;
        p[13] = c9; p[14] = 0.f; p[15] = 0.f;
    }
    if (j <= NORB) {                    // lower_bound over sorted index_ctr
        int lo = 0, hi = NBAS;
        while (lo < hi) {
            int mid = (lo + hi) >> 1;
            if (index_ctr[mid] < j) lo = mid + 1; else hi = mid;
        }
        reinterpret_cast<int*>(ws + WS_START_DW)[j] = lo;
    }
}

// canonical gfx9 wave64 inclusive prefix scan — 6 dependent VALU adds, no LDS pipe
__device__ __forceinline__ float wave_scan_incl(float x) {
    int t;
    t = __builtin_amdgcn_update_dpp(0, __float_as_int(x), 0x111, 0xf, 0xf, false); // row_shr:1
    x += __int_as_float(t);
    t = __builtin_amdgcn_update_dpp(0, __float_as_int(x), 0x112, 0xf, 0xf, false); // row_shr:2
    x += __int_as_float(t);
    t = __builtin_amdgcn_update_dpp(0, __float_as_int(x), 0x114, 0xf, 0xf, false); // row_shr:4
    x += __int_as_float(t);
    t = __builtin_amdgcn_update_dpp(0, __float_as_int(x), 0x118, 0xf, 0xf, false); // row_shr:8
    x += __int_as_float(t);
    t = __builtin_amdgcn_update_dpp(0, __float_as_int(x), 0x142, 0xa, 0xf, false); // row_bcast:15 -> rows 1,3
    x += __int_as_float(t);
    t = __builtin_amdgcn_update_dpp(0, __float_as_int(x), 0x143, 0xc, 0xf, false); // row_bcast:31 -> rows 2,3
    x += __int_as_float(t);
    return x;
}

__global__ __launch_bounds__(256, 5) void ao_kernel(
    const float* __restrict__ inp,     // [NROWS, 3]
    const float* __restrict__ ws,      // params + start
    float* __restrict__ out)           // [NROWS, NORB]
{
    __shared__ __align__(16) float sP[WPB][RPW][NBAS];   // wave-private, 16 KB

    const int tid = threadIdx.x;
    const int w   = tid >> 6, ln = tid & 63;
    const int rowbase = __builtin_amdgcn_readfirstlane(
        (int)blockIdx.x * ROWS_PER_BLOCK + w * RPW);
    const int j0 = ln << 2;            // 4 consecutive bases per lane

    // ---- per-lane params: 4 bases x 16 floats (4x dwordx4 each) ----
    const float4* prm = reinterpret_cast<const float4*>(ws) + (size_t)j0 * 4;
    float nex[4], cc[4], cx[4], cy[4], cz[4];
    float A0[4], A1[4], A2[4], A3[4], B0[4], B1[4], B2[4], B3[4], C9[4];
    #pragma unroll
    for (int k = 0; k < 4; ++k) {
        float4 q0 = prm[k*4+0], q1 = prm[k*4+1], q2 = prm[k*4+2], q3 = prm[k*4+3];
        nex[k] = q0.x; cc[k] = q0.y; cx[k] = q0.z; cy[k] = q0.w;
        cz[k]  = q1.x; A0[k] = q1.y; A1[k] = q1.z; A2[k] = q1.w;
        A3[k]  = q2.x; B0[k] = q2.y; B1[k] = q2.z; B2[k] = q2.w;
        B3[k]  = q3.x; C9[k] = q3.y;
    }
    const int* startp = reinterpret_cast<const int*>(ws + WS_START_DW);
    const int st0 = startp[2*ln], st1 = startp[2*ln+1], st2 = startp[2*ln+2];
    const int i0 = (st0 > 0) ? st0 - 1 : 0;
    const int i1 = (st1 > 0) ? st1 - 1 : 0;
    const int i2 = (st2 > 0) ? st2 - 1 : 0;

    // ---- 4 independent row pipelines: eval -> lane prefix -> DPP wave scan ----
    #pragma unroll
    for (int r = 0; r < RPW; ++r) {
        const int row = rowbase + r;
        float px = inp[row*3+0], py = inp[row*3+1], pz = inp[row*3+2]; // scalar loads
        float ev[4];
        #pragma unroll
        for (int k = 0; k < 4; ++k) {
            float x = px - cx[k], y = py - cy[k], z = pz - cz[k];
            float r2 = fmaf(x, x, fmaf(y, y, z * z));
            float A  = fmaf(A0[k], x, fmaf(A1[k], y, fmaf(A2[k], z, A3[k])));
            float B  = fmaf(B0[k], x, fmaf(B1[k], y, fmaf(B2[k], z, B3[k])));
            float P  = fmaf(C9[k], r2, A * B);
            ev[k] = cc[k] * __builtin_exp2f(nex[k] * r2) * P;
        }
        float e0 = ev[0];
        float e1 = e0 + ev[1];
        float e2 = e1 + ev[2];
        float e3 = e2 + ev[3];
        float s    = wave_scan_incl(e3);
        float excl = s - e3;
        *reinterpret_cast<float4*>(&sP[w][r][j0]) =
            make_float4(e0 + excl, e1 + excl, e2 + excl, e3 + excl);
    }

    // ---- boundary reads (intra-wave lgkmcnt ordering; no barrier) ----
    #pragma unroll
    for (int r = 0; r < RPW; ++r) {
        const int row = rowbase + r;
        float v0 = sP[w][r][i0], v1 = sP[w][r][i1], v2 = sP[w][r][i2];
        float p0 = (st0 > 0) ? v0 : 0.f;
        float p1 = (st1 > 0) ? v1 : 0.f;
        float p2 = (st2 > 0) ? v2 : 0.f;
        *reinterpret_cast<float2*>(&out[(size_t)row * NORB + 2*ln]) =
            make_float2(p1 - p0, p2 - p1);
    }
}

extern "C" void kernel_launch(void* const* d_in, const int* in_sizes, int n_in,
                              void* d_out, int out_size, void* d_ws, size_t ws_size,
                              hipStream_t stream) {
    const float* inp   = (const float*)d_in[0];
    const float* atomc = (const float*)d_in[1];
    const float* bexp  = (const float*)d_in[2];
    const float* bcoef = (const float*)d_in[3];
    const float* bnorm = (const float*)d_in[4];
    // d_in[5] = bas_n (float) — redundant with bas_l, unused
    const int* bl   = (const int*)d_in[6];
    const int* bm   = (const int*)d_in[7];
    const int* bai  = (const int*)d_in[8];
    const int* ictr = (const int*)d_in[9];
    float* out = (float*)d_out;
    float* ws  = (float*)d_ws;

    hipLaunchKernelGGL(setup_kernel, dim3(1), dim3(256), 0, stream,
                       atomc, bexp, bcoef, bnorm, bl, bm, bai, ictr, ws);
    hipLaunchKernelGGL(ao_kernel, dim3(NROWS / ROWS_PER_BLOCK), dim3(256), 0, stream,
                       inp, ws, out);
}

// Round 5
// 20.963 us; speedup vs baseline: 2.1622x; 2.1622x over previous
//
#include <hip/hip_runtime.h>

#define NBATCH 1024
#define NELEC  64
#define NBAS   256
#define NORB   128
#define NROWS  (NBATCH * NELEC)
#define RPB    16   // electron-rows per block

// canonical gfx9 wave64 inclusive prefix scan — 6 dependent VALU adds (DPP),
// no LDS pipe. Verified on HW in round 3 (absmax 9.8e-4).
__device__ __forceinline__ float wave_scan_incl(float x) {
    int t;
    t = __builtin_amdgcn_update_dpp(0, __float_as_int(x), 0x111, 0xf, 0xf, false); // row_shr:1
    x += __int_as_float(t);
    t = __builtin_amdgcn_update_dpp(0, __float_as_int(x), 0x112, 0xf, 0xf, false); // row_shr:2
    x += __int_as_float(t);
    t = __builtin_amdgcn_update_dpp(0, __float_as_int(x), 0x114, 0xf, 0xf, false); // row_shr:4
    x += __int_as_float(t);
    t = __builtin_amdgcn_update_dpp(0, __float_as_int(x), 0x118, 0xf, 0xf, false); // row_shr:8
    x += __int_as_float(t);
    t = __builtin_amdgcn_update_dpp(0, __float_as_int(x), 0x142, 0xa, 0xf, false); // row_bcast:15
    x += __int_as_float(t);
    t = __builtin_amdgcn_update_dpp(0, __float_as_int(x), 0x143, 0xc, 0xf, false); // row_bcast:31
    x += __int_as_float(t);
    return x;
}

__global__ __launch_bounds__(256, 8) void ao_kernel(
    const float* __restrict__ inp,            // [NROWS, 3]
    const float* __restrict__ atom_coords,    // [16, 3]
    const float* __restrict__ bas_exp,        // [NBAS]
    const float* __restrict__ bas_coeffs,     // [NBAS]
    const float* __restrict__ norm_cst,       // [NBAS]
    const int*   __restrict__ bas_l,          // [NBAS]
    const int*   __restrict__ bas_m,          // [NBAS]
    const int*   __restrict__ bas_atom_index, // [NBAS]
    const int*   __restrict__ index_ctr,      // [NBAS] sorted
    float* __restrict__ out)                  // [NROWS, NORB]
{
    __shared__ __align__(16) float s_vals[RPB][NBAS];   // 16 KB; vals then prefix in-place
    __shared__ int s_start[NORB + 1];

    const int tid  = threadIdx.x;
    const int row0 = blockIdx.x * RPB;

    // ---- per-thread basis params: coalesced, register-resident (~13 live) ----
    float ex = bas_exp[tid];
    float cc = norm_cst[tid] * bas_coeffs[tid];
    int   l  = bas_l[tid];
    int   m  = bas_m[tid];
    int   ai = bas_atom_index[tid];
    float cx = atom_coords[ai*3+0], cy = atom_coords[ai*3+1], cz = atom_coords[ai*3+2];

    // start[] without binsearch/barrier: thread j fills o in (idx[j-1], idx[j]]
    int ic   = index_ctr[tid];
    int prev = (tid == 0) ? -1 : index_ctr[tid - 1];
    for (int o = prev + 1; o <= ic; ++o) s_start[o] = tid;
    if (tid == NBAS - 1)
        for (int o = ic + 1; o <= NORB; ++o) s_start[o] = NBAS;

    // fold spherical constant + cc into bilinear form: P = (a.[x,y,z,1])(b.[x,y,z,1]) + c9*r2
    const float C0 = 0.2820948f, C1 = 0.4886025f, C2XY = 1.0925484f,
                C2Z2 = 0.31539156f, C2D = 0.5462742f;
    float a0=0.f,a1=0.f,a2=0.f,a3=0.f, b0=0.f,b1=0.f,b2=0.f,b3=0.f, c9=0.f;
    if (l == 0)            { a3 = cc*C0; b3 = 1.f; }
    else if (l == 1) {
        float s = cc*C1; b3 = 1.f;
        if      (m == -1) a1 = s;
        else if (m ==  0) a2 = s;
        else              a0 = s;
    } else {
        if      (m == -2) { a0 = cc*C2XY; b1 = 1.f; }                       // xy
        else if (m == -1) { a1 = cc*C2XY; b2 = 1.f; }                       // yz
        else if (m ==  0) { float s = cc*3.f*C2Z2; a2 = s; b2 = 1.f; c9 = -s/3.f; } // zz-r2/3
        else if (m ==  1) { a2 = cc*C2XY; b0 = 1.f; }                       // zx
        else              { float s = cc*C2D; a0 = s; a1 = s; b0 = 1.f; b1 = -1.f; } // (x+y)(x-y)
    }
    const float nex = -ex * 1.4426950408889634f;  // fold log2(e) for v_exp_f32

    // ---- phase 1: evaluate basis `tid` for RPB rows (inp loads are wave-uniform) ----
    #pragma unroll
    for (int r = 0; r < RPB; ++r) {
        float px = inp[(row0 + r)*3 + 0];
        float py = inp[(row0 + r)*3 + 1];
        float pz = inp[(row0 + r)*3 + 2];
        float x = px - cx, y = py - cy, z = pz - cz;
        float r2 = fmaf(x, x, fmaf(y, y, z * z));
        float A  = fmaf(a0, x, fmaf(a1, y, fmaf(a2, z, a3)));
        float B  = fmaf(b0, x, fmaf(b1, y, fmaf(b2, z, b3)));
        float P  = fmaf(c9, r2, A * B);
        s_vals[r][tid] = __builtin_exp2f(nex * r2) * P;
    }
    __syncthreads();   // the ONLY barrier

    // ---- phase 2: wave w owns rows 4w..4w+3 end-to-end (no more barriers) ----
    const int w = tid >> 6, ln = tid & 63;
    #pragma unroll
    for (int r = 0; r < 4; ++r) {
        const int row = 4*w + r;
        float4 v = *reinterpret_cast<const float4*>(&s_vals[row][ln << 2]);
        float e0 = v.x;
        float e1 = e0 + v.y;
        float e2 = e1 + v.z;
        float e3 = e2 + v.w;
        float s    = wave_scan_incl(e3);
        float excl = s - e3;
        *reinterpret_cast<float4*>(&s_vals[row][ln << 2]) =
            make_float4(e0 + excl, e1 + excl, e2 + excl, e3 + excl);
    }

    // ---- phase 3: boundary diffs, 4 orbitals/lane, 2 rows per pass ----
    #pragma unroll
    for (int g = 0; g < 2; ++g) {
        const int row = 4*w + 2*g + (ln >> 5);   // block-local row
        const int q   = (ln & 31) << 2;
        int st[5];
        #pragma unroll
        for (int k = 0; k < 5; ++k) st[k] = s_start[q + k];
        float p[5];
        #pragma unroll
        for (int k = 0; k < 5; ++k) {
            int idx = st[k] - 1;
            float v = s_vals[row][idx < 0 ? 0 : idx];
            p[k] = (st[k] > 0) ? v : 0.0f;
        }
        float4 o4 = make_float4(p[1]-p[0], p[2]-p[1], p[3]-p[2], p[4]-p[3]);
        // GLOBAL row = row0 + row (round-4 bug: missing row0)
        *reinterpret_cast<float4*>(&out[(size_t)(row0 + row) * NORB + q]) = o4;
    }
}

extern "C" void kernel_launch(void* const* d_in, const int* in_sizes, int n_in,
                              void* d_out, int out_size, void* d_ws, size_t ws_size,
                              hipStream_t stream) {
    const float* inp   = (const float*)d_in[0];
    const float* atomc = (const float*)d_in[1];
    const float* bexp  = (const float*)d_in[2];
    const float* bcoef = (const float*)d_in[3];
    const float* bnorm = (const float*)d_in[4];
    // d_in[5] = bas_n (float) — redundant with bas_l, unused
    const int* bl   = (const int*)d_in[6];
    const int* bm   = (const int*)d_in[7];
    const int* bai  = (const int*)d_in[8];
    const int* ictr = (const int*)d_in[9];
    float* out = (float*)d_out;

    hipLaunchKernelGGL(ao_kernel, dim3(NROWS / RPB), dim3(256), 0, stream,
                       inp, atomc, bexp, bcoef, bnorm, bl, bm, bai, ictr, out);
}